// Round 11
// baseline (226.938 us; speedup 1.0000x reference)
//
#include <hip/hip_runtime.h>
#include <math.h>

#define NN 50000
#define NE 600000
#define D 128
#define NH 3
#define CAP 64                              // max degree bucket == wave size
#define CSTRIDE 16                          // counts padded: 1 dst per 64B line
#define EDGE_BLOCKS ((NE + 255) / 256)      // 2344
#define MFMA_BLOCKS ((NN + 63) / 64)        // 782
#define LOG2E 1.44269504088896340736f

typedef short bf16x8 __attribute__((ext_vector_type(8)));
typedef _Float16 f16x8 __attribute__((ext_vector_type(8)));
typedef float f32x4 __attribute__((ext_vector_type(4)));

extern "C" __device__ float __ocml_native_exp2_f32(float);   // single v_exp_f32

__device__ __forceinline__ unsigned short f2b(float f) {
  unsigned int u = __float_as_uint(f);
  u += 0x7FFF + ((u >> 16) & 1);            // round-to-nearest-even
  return (unsigned short)(u >> 16);
}
__device__ __forceinline__ float blo(unsigned int u) {
  return __uint_as_float(u << 16);
}
__device__ __forceinline__ float bhi(unsigned int u) {
  return __uint_as_float(u & 0xffff0000u);
}
__device__ __forceinline__ unsigned short f2h(float f) {
  _Float16 t = (_Float16)f;
  return *(unsigned short*)&t;
}

// ---------------------------------------------------------------------------
// pack_scatter2: unchanged r10 (control). Scatter ~45us = device-atomic
// throughput floor (r10 falsifier: line padding only -5us, VALUBusy 0.65%).
// ---------------------------------------------------------------------------
__global__ __launch_bounds__(256) void pack_scatter2(const float* __restrict__ W_lin,
                                                     const float* __restrict__ W_heads,
                                                     const float* __restrict__ att_src,
                                                     const float* __restrict__ att_dst,
                                                     const float* __restrict__ b_lin,
                                                     const float* __restrict__ bias_heads,
                                                     const int* __restrict__ ei,
                                                     const int* __restrict__ eid,
                                                     const float* __restrict__ ddi,
                                                     const float* __restrict__ emb,
                                                     uint4* __restrict__ Bpack,
                                                     uint4* __restrict__ Wpack3,
                                                     float* __restrict__ sbuf,
                                                     float* __restrict__ bcomb2,
                                                     int* __restrict__ counts,
                                                     unsigned int* __restrict__ slots8) {
  const int bx = blockIdx.x;
  const int tid = threadIdx.x;
  if (bx < EDGE_BLOCKS) {
    int e = bx * 256 + tid;
    if (e < NE) {
      int src = ei[e], dst = ei[NE + e];
      int idx = atomicAdd(&counts[dst * CSTRIDE], 1);
      idx = idx < CAP ? idx : CAP - 1;   // safety clamp (statistically unreachable)
      float ew = emb[eid[e]] - ddi[e];
      slots8[dst * CAP + idx] = (unsigned int)src | ((unsigned int)f2b(ew) << 16);
    }
    return;
  }
  const int pb = bx - EDGE_BLOCKS;
  if (pb < 8) {
    int r = pb * 256 + tid;              // 0..2047
    int nt = r >> 8, s = (r >> 6) & 3, q = (r >> 4) & 3, n0 = r & 15;
    int kbase = s * 32 + q * 8;
    int n = nt * 16 + n0;
    unsigned int w[4];
    #pragma unroll
    for (int p = 0; p < 4; ++p) {
      unsigned short lo = f2b(W_lin[(kbase + 2 * p) * D + n]);
      unsigned short hi = f2b(W_lin[(kbase + 2 * p + 1) * D + n]);
      w[p] = (unsigned int)lo | ((unsigned int)hi << 16);
    }
    Bpack[r] = make_uint4(w[0], w[1], w[2], w[3]);
  } else if (pb < 32) {
    int u = (pb - 8) * 256 + tid;        // 0..6143
    int h = u >> 11, r = u & 2047;
    int nt = r >> 8, s = (r >> 6) & 3, q = (r >> 4) & 3, n0 = r & 15;
    int kbase = s * 32 + q * 8;
    int n = nt * 16 + n0;
    const float* W = W_heads + (size_t)h * D * D;
    unsigned int w[4];
    #pragma unroll
    for (int p = 0; p < 4; ++p) {
      unsigned short lo = f2h(W[(kbase + 2 * p) * D + n]);
      unsigned short hi = f2h(W[(kbase + 2 * p + 1) * D + n]);
      w[p] = (unsigned int)lo | ((unsigned int)hi << 16);
    }
    Wpack3[h * 2048 + r] = make_uint4(w[0], w[1], w[2], w[3]);
  } else if (pb < 35) {
    const int h = pb - 32;
    __shared__ float wha_s[128], wha_d[128], scs[128], scd[128];
    {
      int m = tid & 127;
      const float* W = W_heads + (size_t)h * D * D + m * D;
      const float* a = (tid < 128) ? (att_src + h * D) : (att_dst + h * D);
      float acc = 0.f;
      for (int n = 0; n < D; ++n) acc += W[n] * a[n];
      if (tid < 128) wha_s[m] = acc; else wha_d[m] = acc;
    }
    __syncthreads();
    {
      int k = tid & 127;
      const float* wl = W_lin + k * D;
      const float* wha = (tid < 128) ? wha_s : wha_d;
      float acc = 0.f;
      for (int m = 0; m < D; ++m) acc += wl[m] * wha[m];
      if (tid < 128) scs[k] = acc * LOG2E; else scd[k] = acc * LOG2E;
    }
    __syncthreads();
    if (tid < 2) {
      const float* wha = tid ? wha_d : wha_s;
      float a = 0.f;
      for (int k = 0; k < D; ++k) a += b_lin[k] * wha[k];
      sbuf[h * 2 + tid] = a * LOG2E;     // sbuf = [s0,d0,s1,d1,s2,d2] (scaled)
    }
    {
      int s = (tid >> 6) & 3, q = (tid >> 4) & 3, n0 = tid & 15;
      int kbase = s * 32 + q * 8;
      bool mine = (n0 < 6) && ((n0 >> 1) == h);
      bool zero = (h == 0) && (n0 >= 6);
      if (mine || zero) {
        float vals[8];
        #pragma unroll
        for (int j = 0; j < 8; ++j)
          vals[j] = zero ? 0.f : ((n0 & 1) ? scd[kbase + j] : scs[kbase + j]);
        unsigned int w[4];
        #pragma unroll
        for (int p = 0; p < 4; ++p)
          w[p] = (unsigned int)f2b(vals[2 * p]) | ((unsigned int)f2b(vals[2 * p + 1]) << 16);
        Bpack[2048 + tid] = make_uint4(w[0], w[1], w[2], w[3]);
      }
    }
  } else {
    if (tid < D)
      bcomb2[tid] = (bias_heads[tid] + bias_heads[D + tid] + bias_heads[2 * D + tid]) * (1.f / 3.f);
  }
}

// ---------------------------------------------------------------------------
// mfma_x: unchanged (control).
// ---------------------------------------------------------------------------
__global__ __launch_bounds__(256) void mfma_x(const float* __restrict__ x,
                                              const uint4* __restrict__ Bpack,
                                              const float* __restrict__ b_lin,
                                              const float* __restrict__ sbuf,
                                              unsigned short* __restrict__ xb,
                                              float* __restrict__ s_src4,
                                              float* __restrict__ s_dst4) {
  const int row0 = blockIdx.x * 64;
  const int tid = threadIdx.x;
  __shared__ __align__(16) unsigned short As[64][136];
  #pragma unroll
  for (int it = 0; it < 8; ++it) {
    int idx = tid + it * 256;
    int m = idx >> 5, k4 = idx & 31;
    int row = row0 + m;
    float4 v = make_float4(0.f, 0.f, 0.f, 0.f);
    if (row < NN) v = ((const float4*)(x + (size_t)row * D))[k4];
    uint2 pk;
    pk.x = (unsigned int)f2b(v.x) | ((unsigned int)f2b(v.y) << 16);
    pk.y = (unsigned int)f2b(v.z) | ((unsigned int)f2b(v.w) << 16);
    *((uint2*)&As[m][k4 * 4]) = pk;
  }
  __syncthreads();
  const int wv = tid >> 6;
  const int lane = tid & 63;
  const int n0 = lane & 15, q = lane >> 4;
  const int boff = q * 16 + n0;
  const bf16x8* Bp = (const bf16x8*)Bpack;

  bf16x8 a4[4];
  #pragma unroll
  for (int s = 0; s < 4; ++s)
    a4[s] = *(const bf16x8*)&As[wv * 16 + n0][s * 32 + q * 8];

  f32x4 acc[9];
  #pragma unroll
  for (int nt = 0; nt < 9; ++nt) acc[nt] = (f32x4){0.f, 0.f, 0.f, 0.f};

  #pragma unroll
  for (int s = 0; s < 4; ++s) {
    #pragma unroll
    for (int nt = 0; nt < 9; ++nt) {
      bf16x8 b = Bp[(nt * 4 + s) * 64 + boff];
      acc[nt] = __builtin_amdgcn_mfma_f32_16x16x32_bf16(a4[s], b, acc[nt], 0, 0, 0);
    }
  }
  __syncthreads();   // all waves hoisted a4; As now dead -> reuse as out-tile
  #pragma unroll
  for (int nt = 0; nt < 8; ++nt) {
    int col = nt * 16 + n0;
    float bv = b_lin[col];
    #pragma unroll
    for (int r = 0; r < 4; ++r)
      As[wv * 16 + q * 4 + r][col] = f2b(acc[nt][r] + bv);
  }
  // score cols: n0 even -> s_src4[row*4 + n0/2], odd -> s_dst4[row*4 + n0/2]
  if (n0 < 6) {
    float sb = sbuf[n0];
    float* Sout = (n0 & 1) ? s_dst4 : s_src4;
    #pragma unroll
    for (int r = 0; r < 4; ++r) {
      int row = row0 + wv * 16 + q * 4 + r;
      if (row < NN) Sout[row * 4 + (n0 >> 1)] = acc[8][r] + sb;
    }
  }
  __syncthreads();
  // coalesced write-out: 64 rows x 128 bf16 = 1024 uint4
  #pragma unroll
  for (int i = 0; i < 4; ++i) {
    int idx = tid + i * 256;          // 0..1023
    int row = idx >> 4, c16 = idx & 15;
    int grow = row0 + row;
    if (grow < NN)
      *((uint4*)&xb[(size_t)grow * D + c16 * 8]) = *((const uint4*)&As[row][c16 * 8]);
  }
}

// ---------------------------------------------------------------------------
// gather13: wave-parallel edge setup. Old structure recomputed the per-edge
// scalar chain (add+leaky+exp2+w-mul ~15 ops) redundantly in all 32 lanes of
// a half-wave (43% of VALU duplicated 32x). Now: lane l owns slot l (CAP=64
// == wave size), computes its edge's (w0,w1,w2,p) ONCE in parallel; denoms
// via one butterfly; then a broadcast loop (shfl with wave-uniform k ->
// readlane) where each lane accumulates 2 channels (1 dword load + 2 unpack
// + 6 FMA per edge, 4-deep rolling prefetch keeps loads off the chain).
// ---------------------------------------------------------------------------
__global__ __launch_bounds__(64) void gather13(const int* __restrict__ counts,
                                               const unsigned int* __restrict__ slots8,
                                               const float4* __restrict__ s_src4,
                                               const float4* __restrict__ s_dst4,
                                               const unsigned short* __restrict__ xb,
                                               unsigned short* __restrict__ accb) {
  const int dst = blockIdx.x;
  const int lane = threadIdx.x;          // 0..63
  int cnt = counts[dst * CSTRIDE];
  cnt = cnt < CAP ? cnt : CAP;
  const bool valid = lane < cnt;
  float4 sd = s_dst4[dst];

  // ---- parallel per-edge setup: one edge per lane ----
  unsigned int se = slots8[dst * CAP + lane];     // always in-bounds
  int src = valid ? (int)(se & 0xffffu) : 0;
  float ew = bhi(se);
  float4 ss = s_src4[src];
  float v0 = ss.x + sd.x, v1 = ss.y + sd.y, v2 = ss.z + sd.z;
  v0 = fmaxf(v0, 0.2f * v0);             // leaky(v) == max(v, 0.2v)
  v1 = fmaxf(v1, 0.2f * v1);
  v2 = fmaxf(v2, 0.2f * v2);
  float p0 = __ocml_native_exp2_f32(v0); // scores pre-scaled by log2(e)
  float p1 = __ocml_native_exp2_f32(v1);
  float p2 = __ocml_native_exp2_f32(v2);
  p0 = valid ? p0 : 0.f;
  p1 = valid ? p1 : 0.f;
  p2 = valid ? p2 : 0.f;
  float w0 = p0 * ew, w1 = p1 * ew, w2 = p2 * ew;

  // ---- denominators: 64-lane butterfly (all lanes get the sum) ----
  float d0 = p0, d1 = p1, d2 = p2;
  #pragma unroll
  for (int off = 1; off < 64; off <<= 1) {
    d0 += __shfl_xor(d0, off, 64);
    d1 += __shfl_xor(d1, off, 64);
    d2 += __shfl_xor(d2, off, 64);
  }

  // ---- broadcast accumulate: lane handles channels {2*lane, 2*lane+1} ----
  float a00 = 0.f, a01 = 0.f, a10 = 0.f, a11 = 0.f, a20 = 0.f, a21 = 0.f;
  unsigned int ubuf[4];
  const int npre = cnt < 4 ? cnt : 4;
  for (int kp = 0; kp < npre; ++kp) {
    int sk = __shfl(src, kp, 64);
    ubuf[kp] = *(const unsigned int*)&xb[(size_t)sk * D + lane * 2];
  }
  for (int k = 0; k < cnt; ++k) {
    unsigned int u = ubuf[k & 3];
    int kn = k + 4;
    if (kn < cnt) {
      int sk = __shfl(src, kn, 64);
      ubuf[kn & 3] = *(const unsigned int*)&xb[(size_t)sk * D + lane * 2];
    }
    float w0k = __shfl(w0, k, 64);
    float w1k = __shfl(w1, k, 64);
    float w2k = __shfl(w2, k, 64);
    float xl = blo(u), xh = bhi(u);
    a00 += w0k * xl; a01 += w0k * xh;
    a10 += w1k * xl; a11 += w1k * xh;
    a20 += w2k * xl; a21 += w2k * xh;
  }

  // ---- normalize + fp16 pack; lane writes one dword per head ----
  float r0 = 1.f / (3.f * fmaxf(d0, 1e-16f));   // fold 1/NH here
  float r1 = 1.f / (3.f * fmaxf(d1, 1e-16f));
  float r2 = 1.f / (3.f * fmaxf(d2, 1e-16f));
  unsigned short* base = accb + (size_t)dst * (NH * D);
  *(unsigned int*)&base[2 * lane] =
      (unsigned int)f2h(a00 * r0) | ((unsigned int)f2h(a01 * r0) << 16);
  *(unsigned int*)&base[D + 2 * lane] =
      (unsigned int)f2h(a10 * r1) | ((unsigned int)f2h(a11 * r1) << 16);
  *(unsigned int*)&base[2 * D + 2 * lane] =
      (unsigned int)f2h(a20 * r2) | ((unsigned int)f2h(a21 * r2) << 16);
}

// ---------------------------------------------------------------------------
// final_gemm16: unchanged (control). Single-pass f16 MFMA.
// ---------------------------------------------------------------------------
__global__ __launch_bounds__(256) void final_gemm16(const unsigned short* __restrict__ accb,
                                                    const uint4* __restrict__ Wpack3,
                                                    const float* __restrict__ bcomb2,
                                                    float* __restrict__ out) {
  const int row0 = blockIdx.x * 64;
  const int tid = threadIdx.x;
  __shared__ __align__(16) _Float16 Af[64][136];
  const int wv = tid >> 6;
  const int lane = tid & 63;
  const int n0 = lane & 15, q = lane >> 4;
  const int boff = q * 16 + n0;

  f32x4 o[8];
  #pragma unroll
  for (int nt = 0; nt < 8; ++nt) o[nt] = (f32x4){0.f, 0.f, 0.f, 0.f};

  for (int ck = 0; ck < NH; ++ck) {
    if (ck) __syncthreads();              // prior frag reads done before restage
    #pragma unroll
    for (int it = 0; it < 4; ++it) {
      int idx = tid + it * 256;           // 0..1023
      int m = idx >> 4, k8 = idx & 15;
      int row = row0 + m;
      uint4 u = make_uint4(0, 0, 0, 0);
      if (row < NN)
        u = *(const uint4*)&accb[(size_t)row * (NH * D) + ck * D + k8 * 8];
      *((uint4*)&Af[m][k8 * 8]) = u;      // direct copy: accb is already fp16
    }
    __syncthreads();
    f16x8 af[4];
    #pragma unroll
    for (int s = 0; s < 4; ++s)
      af[s] = *(const f16x8*)&Af[wv * 16 + n0][s * 32 + q * 8];
    const f16x8* Bp = (const f16x8*)(Wpack3 + ck * 2048);
    #pragma unroll
    for (int s = 0; s < 4; ++s) {
      #pragma unroll
      for (int nt = 0; nt < 8; ++nt) {
        f16x8 b = Bp[(nt * 4 + s) * 64 + boff];
        o[nt] = __builtin_amdgcn_mfma_f32_16x16x32_f16(af[s], b, o[nt], 0, 0, 0);
      }
    }
  }
  // epilogue: 16-lane groups write 64B-contiguous fp32 segments
  #pragma unroll
  for (int nt = 0; nt < 8; ++nt) {
    int col = nt * 16 + n0;
    float bv = bcomb2[col];
    #pragma unroll
    for (int r = 0; r < 4; ++r) {
      int row = row0 + wv * 16 + q * 4 + r;
      if (row < NN) out[(size_t)row * D + col] = o[nt][r] + bv;
    }
  }
}

// ---------------------------------------------------------------------------
extern "C" void kernel_launch(void* const* d_in, const int* in_sizes, int n_in,
                              void* d_out, int out_size, void* d_ws, size_t ws_size,
                              hipStream_t stream) {
  const float* x          = (const float*)d_in[0];
  const int*   ei         = (const int*)d_in[1];
  const int*   eid        = (const int*)d_in[2];
  const float* ddi        = (const float*)d_in[3];
  const float* W_lin      = (const float*)d_in[4];
  const float* b_lin      = (const float*)d_in[5];
  const float* emb        = (const float*)d_in[6];
  const float* W_heads    = (const float*)d_in[7];
  const float* att_src    = (const float*)d_in[8];
  const float* att_dst    = (const float*)d_in[9];
  const float* bias_heads = (const float*)d_in[10];
  float* out = (float*)d_out;

  // workspace layout (16B-aligned chunks first); total ~69 MB
  uint4*  Bpack  = (uint4*)d_ws;                               // 2304 (W_lin | 6 score cols)
  uint4*  Wpack3 = Bpack + 2304;                               // 3*2048 (W_heads fp16)
  unsigned short* xb = (unsigned short*)(Wpack3 + NH * 2048);  // NN*D bf16 (12.8MB)
  unsigned int* slots8 = (unsigned int*)(xb + (size_t)NN * D); // NN*CAP (12.8MB)
  unsigned short* accb = (unsigned short*)(slots8 + (size_t)NN * CAP); // NN*384 fp16 (38.4MB)
  float*  sbuf   = (float*)(accb + (size_t)NN * NH * D);       // 8
  float*  bcomb2 = sbuf + 8;                                   // 128
  float*  s_src4 = bcomb2 + 128;                               // NN*4 (stride-4)
  float*  s_dst4 = s_src4 + (size_t)NN * 4;                    // NN*4
  int*    counts = (int*)(s_dst4 + (size_t)NN * 4);            // NN*CSTRIDE (3.2MB, line-padded)

  // 0. zero padded bucket counts (3.2MB)
  hipMemsetAsync(counts, 0, (size_t)NN * CSTRIDE * sizeof(int), stream);
  // 1. scatter (t=0, padded atomics) + W repacks + score cols + bcomb2 (control)
  pack_scatter2<<<EDGE_BLOCKS + 36, 256, 0, stream>>>(
      W_lin, W_heads, att_src, att_dst, b_lin, bias_heads, ei, eid, ddi, emb,
      Bpack, Wpack3, sbuf, bcomb2, counts, slots8);
  // 2. x_tilde + score columns (control)
  mfma_x<<<MFMA_BLOCKS, 256, 0, stream>>>(x, Bpack, b_lin, sbuf, xb,
                                          s_src4, s_dst4);
  // 3. per-dst gather: wave-parallel setup, broadcast accumulate
  gather13<<<NN, 64, 0, stream>>>(counts, slots8, (const float4*)s_src4,
                                  (const float4*)s_dst4, xb, accb);
  // 4. dense epilogue (control)
  final_gemm16<<<MFMA_BLOCKS, 256, 0, stream>>>(accb, Wpack3, bcomb2, out);
}